// Round 4
// baseline (114.815 us; speedup 1.0000x reference)
//
#include <hip/hip_runtime.h>

// Radix2ModGroup: per 8-element group, quantize to int magnitude (SF=0.05,
// |q|<=255), keep the 12 largest-exponent power-of-two terms across the
// group's 64 (element,bit) candidates (ties -> lowest element index),
// reconstruct.
//
// Lane-paired layout: each lane owns ONE float4 (half a group) so global
// loads/stores are perfectly contiguous 16B/lane. Lane pairs (2j, 2j+1)
// exchange packed magnitudes with one __shfl_xor and both redundantly run
// the branchless top-12 selection on the group's 64-bit candidate word:
// after an 8x8 bit-transpose, bit position 8*e + (7-i) encodes candidate
// (exponent e, element i), so bit position is a strict selection priority
// and "top-12 terms" == "top-12 set bits" (rank-select, no branches).

constexpr float SF = 0.05f;
constexpr int NUM_EXPS = 12;

typedef float vfloat4 __attribute__((ext_vector_type(4)));  // native vector
                                                            // (nontemporal
                                                            // builtins reject
                                                            // HIP_vector_type)

__device__ __forceinline__ unsigned long long transpose8x8(unsigned long long x) {
  // bit(8r+c) <-> bit(8c+r)  (Hacker's Delight 8x8 bit-matrix transpose)
  unsigned long long t;
  t = (x ^ (x >> 7)) & 0x00AA00AA00AA00AAull; x ^= t ^ (t << 7);
  t = (x ^ (x >> 14)) & 0x0000CCCC0000CCCCull; x ^= t ^ (t << 14);
  t = (x ^ (x >> 28)) & 0x00000000F0F0F0F0ull; x ^= t ^ (t << 28);
  return x;
}

__global__ __launch_bounds__(256) void radix2_mod_group_kernel(
    const vfloat4* __restrict__ xv, vfloat4* __restrict__ ov, int nvec) {
  int t = blockIdx.x * blockDim.x + threadIdx.x;
  if (t >= nvec) return;

  vfloat4 a = __builtin_nontemporal_load(&xv[t]);
  float v[4] = {a.x, a.y, a.z, a.w};

  // Quantize own 4 elements; pack |q_j| into byte (3-j) of m4.
  unsigned m4 = 0u;
#pragma unroll
  for (int j = 0; j < 4; ++j) {
    // jnp.round == round-half-to-even -> rintf (RTNE). Division stays IEEE
    // (x * 20.0f is NOT bit-exact vs x / 0.05f).
    float r = rintf(v[j] / SF);
    r = fminf(fmaxf(r, -255.0f), 255.0f);
    int q = (int)r;
    unsigned mi = (unsigned)(q < 0 ? -q : q);
    m4 |= mi << (8 * (3 - j));
  }

  // Pair lanes: even lane holds group elements 0-3, odd lane 4-7.
  unsigned oth = __shfl_xor(m4, 1, 64);
  bool evn = ((threadIdx.x & 1) == 0);
  unsigned hi = evn ? m4 : oth;   // elements 0-3 -> bytes 7..4
  unsigned lo = evn ? oth : m4;   // elements 4-7 -> bytes 3..0
  unsigned long long M = ((unsigned long long)hi << 32) | (unsigned long long)lo;

  // w bit (8e + (7-i)) = bit e of mag_i. Position = selection priority.
  unsigned long long w = transpose8x8(M);

  // Drop the jj = max(P-12, 0) lowest-priority set bits.
  int P = __popcll(w);
  int jj = P > NUM_EXPS ? P - NUM_EXPS : 0;

  // Branchless rank-select: pos = index of the (jj+1)-th set bit from LSB.
  unsigned long long xx = w;
  int pos = 0;
  int c;
  c = __popcll(xx & 0xffffffffull);
  { int s = (jj >= c); pos += s << 5; jj -= s ? c : 0; xx = s ? (xx >> 32) : xx; }
  c = __popc((unsigned)xx & 0xffffu);
  { int s = (jj >= c); pos += s << 4; jj -= s ? c : 0; xx = s ? (xx >> 16) : xx; }
  c = __popc((unsigned)xx & 0xffu);
  { int s = (jj >= c); pos += s << 3; jj -= s ? c : 0; xx = s ? (xx >> 8) : xx; }
  c = __popc((unsigned)xx & 0xfu);
  { int s = (jj >= c); pos += s << 2; jj -= s ? c : 0; xx = s ? (xx >> 4) : xx; }
  c = __popc((unsigned)xx & 0x3u);
  { int s = (jj >= c); pos += s << 1; jj -= s ? c : 0; xx = s ? (xx >> 2) : xx; }
  c = (int)((unsigned)xx & 1u);
  { int s = (jj >= c); pos += s; }

  unsigned long long keep = w & (~0ull << pos);

  // Transpose back: byte (7-i) of Kt = kept magnitude of element i.
  unsigned long long Kt = transpose8x8(keep);

  // Own half: even lane -> bytes 7..4 (high word), odd -> bytes 3..0.
  unsigned Kmine = evn ? (unsigned)(Kt >> 32) : (unsigned)Kt;

  vfloat4 o;
#pragma unroll
  for (int j = 0; j < 4; ++j) {
    unsigned mi = (Kmine >> (8 * (3 - j))) & 0xffu;
    // sign of q == sign of x whenever mag != 0; mag==0 -> +/-0 == 0.
    o[j] = copysignf((float)mi * SF, v[j]);
  }

  __builtin_nontemporal_store(o, &ov[t]);
}

extern "C" void kernel_launch(void* const* d_in, const int* in_sizes, int n_in,
                              void* d_out, int out_size, void* d_ws, size_t ws_size,
                              hipStream_t stream) {
  const float* x = (const float*)d_in[0];
  float* out = (float*)d_out;
  int n = in_sizes[0];
  int nvec = n / 4;
  int block = 256;
  int grid = (nvec + block - 1) / block;
  radix2_mod_group_kernel<<<grid, block, 0, stream>>>(
      (const vfloat4*)x, (vfloat4*)out, nvec);
}